// Round 1
// baseline (1824.677 us; speedup 1.0000x reference)
//
#include <hip/hip_runtime.h>
#include <hip/hip_bf16.h>

#define NS   32768
#define DD   256
#define NPOS 4
#define IDN  4096
#define EPSV 1e-6f

#define BM 128
#define BN 128
#define BK 16

// ---------------- small prep kernels ----------------

__global__ void count_k(const int* __restrict__ targets, float* cnt) {
    int i = blockIdx.x * 256 + threadIdx.x;
    if (i < NS) atomicAdd(&cnt[targets[i]], 1.0f);
}

__global__ void accum_k(const float* __restrict__ inputs,
                        const int* __restrict__ targets, float* centers) {
    size_t idx = (size_t)blockIdx.x * 256 + threadIdx.x;   // over NS*DD
    int i = (int)(idx >> 8);       // DD == 256
    int d = (int)(idx & 255);
    atomicAdd(&centers[(size_t)targets[i] * DD + d], inputs[idx]);
}

__global__ void fin_centers_k(float* centers, const float* __restrict__ cnt,
                              const int* __restrict__ targets,
                              float* c2, int* cid) {
    int c = blockIdx.x;
    int d = threadIdx.x;
    float v = centers[(size_t)c * DD + d] / cnt[c];
    centers[(size_t)c * DD + d] = v;
    float sq = v * v;
    #pragma unroll
    for (int m = 1; m < 64; m <<= 1) sq += __shfl_xor(sq, m, 64);
    __shared__ float sb[4];
    int lane = d & 63, w = d >> 6;
    if (lane == 0) sb[w] = sq;
    __syncthreads();
    if (d == 0) {
        c2[c] = sb[0] + sb[1] + sb[2] + sb[3];
        cid[c] = targets[c * NPOS];
    }
}

__global__ void x2_k(const float* __restrict__ inputs, float* x2) {
    int i = blockIdx.x;
    int d = threadIdx.x;
    float v = inputs[(size_t)i * DD + d];
    float sq = v * v;
    #pragma unroll
    for (int m = 1; m < 64; m <<= 1) sq += __shfl_xor(sq, m, 64);
    __shared__ float sb[4];
    int lane = d & 63, w = d >> 6;
    if (lane == 0) sb[w] = sq;
    __syncthreads();
    if (d == 0) x2[i] = sb[0] + sb[1] + sb[2] + sb[3];
}

__global__ void dneg_k(const float* __restrict__ negsum,
                       const float* __restrict__ negcnt, float* dneg) {
    int c = blockIdx.x * 256 + threadIdx.x;
    if (c < IDN) dneg[c] = negsum[c] / fmaxf(negcnt[c], 1.0f);
}

// ---------------- fused distance + mining pass ----------------
// PASS 1: per-center neg sum/cnt (-> d_neg) + global pos sum/cnt
// PASS 2: per-center hard-neg sum/cnt (dist < d_neg)

template <int PASS>
__global__ __launch_bounds__(256)
void pass_k(const float* __restrict__ A,      // centers [IDN][DD]
            const float* __restrict__ X,      // inputs  [NS][DD]
            const float* __restrict__ c2,
            const float* __restrict__ x2,
            const int*   __restrict__ targets,
            const int*   __restrict__ cid,
            float* negsum, float* negcnt,
            const float* __restrict__ dneg,
            float* hardsum, float* hardcnt,
            float* scal) {
    __shared__ __align__(16) float As[BK][BM];
    __shared__ __align__(16) float Bs[BK][BN];
    __shared__ float red[8];

    const int tid = threadIdx.x;
    const int tx = tid & 15;
    const int ty = tid >> 4;
    const int bm = blockIdx.y;
    const int bn = blockIdx.x;

    float acc[8][8];
    #pragma unroll
    for (int a = 0; a < 8; ++a)
        #pragma unroll
        for (int b = 0; b < 8; ++b) acc[a][b] = 0.f;

    const int r0 = tid >> 2;
    const int k4 = (tid & 3) << 2;

    for (int k0 = 0; k0 < DD; k0 += BK) {
        #pragma unroll
        for (int s = 0; s < 2; ++s) {
            int r = r0 + s * 64;
            float4 av = *(const float4*)&A[(size_t)(bm * BM + r) * DD + k0 + k4];
            As[k4 + 0][r] = av.x; As[k4 + 1][r] = av.y;
            As[k4 + 2][r] = av.z; As[k4 + 3][r] = av.w;
            float4 bv = *(const float4*)&X[(size_t)(bn * BN + r) * DD + k0 + k4];
            Bs[k4 + 0][r] = bv.x; Bs[k4 + 1][r] = bv.y;
            Bs[k4 + 2][r] = bv.z; Bs[k4 + 3][r] = bv.w;
        }
        __syncthreads();
        #pragma unroll
        for (int kk = 0; kk < BK; ++kk) {
            float4 a0 = *(const float4*)&As[kk][ty * 8];
            float4 a1 = *(const float4*)&As[kk][ty * 8 + 4];
            float4 b0 = *(const float4*)&Bs[kk][tx * 8];
            float4 b1 = *(const float4*)&Bs[kk][tx * 8 + 4];
            float av[8] = {a0.x, a0.y, a0.z, a0.w, a1.x, a1.y, a1.z, a1.w};
            float bv[8] = {b0.x, b0.y, b0.z, b0.w, b1.x, b1.y, b1.z, b1.w};
            #pragma unroll
            for (int a = 0; a < 8; ++a)
                #pragma unroll
                for (int b = 0; b < 8; ++b)
                    acc[a][b] = fmaf(av[a], bv[b], acc[a][b]);
        }
        __syncthreads();
    }

    // ---- epilogue: dist + mining, row-reduce over the 16 tx threads ----
    const int gr = bm * BM + ty * 8;
    const int gc = bn * BN + tx * 8;
    float x2v[8]; int tg[8];
    #pragma unroll
    for (int b = 0; b < 8; ++b) { x2v[b] = x2[gc + b]; tg[b] = targets[gc + b]; }

    float psum = 0.f, pcnt = 0.f;

    #pragma unroll
    for (int a = 0; a < 8; ++a) {
        const int c = gr + a;
        const int cd = cid[c];
        const float c2v = c2[c];
        float dn = 0.f;
        if (PASS == 2) dn = dneg[c];
        float s0 = 0.f, s1 = 0.f;
        #pragma unroll
        for (int b = 0; b < 8; ++b) {
            float d2 = c2v + x2v[b] - 2.f * acc[a][b];
            float dist = sqrtf(fmaxf(d2, 1e-12f));
            bool valid = dist > EPSV;
            bool neg = (cd != tg[b]);
            if (PASS == 1) {
                if (neg) {
                    if (valid) { s0 += dist; s1 += 1.f; }
                } else if (valid) {
                    psum += dist; pcnt += 1.f;
                }
            } else {
                if (neg && valid && dist < dn) { s0 += dist; s1 += 1.f; }
            }
        }
        #pragma unroll
        for (int m = 1; m < 16; m <<= 1) {
            s0 += __shfl_xor(s0, m, 64);
            s1 += __shfl_xor(s1, m, 64);
        }
        if (tx == 0) {
            if (PASS == 1) {
                atomicAdd(&negsum[c], s0);
                atomicAdd(&negcnt[c], s1);
            } else {
                atomicAdd(&hardsum[c], s0);
                atomicAdd(&hardcnt[c], s1);
            }
        }
    }

    if (PASS == 1) {
        #pragma unroll
        for (int m = 1; m < 64; m <<= 1) {
            psum += __shfl_xor(psum, m, 64);
            pcnt += __shfl_xor(pcnt, m, 64);
        }
        int lane = tid & 63, w = tid >> 6;
        if (lane == 0) { red[w] = psum; red[4 + w] = pcnt; }
        __syncthreads();
        if (tid == 0) {
            atomicAdd(&scal[0], red[0] + red[1] + red[2] + red[3]);
            atomicAdd(&scal[1], red[4] + red[5] + red[6] + red[7]);
        }
    }
}

__global__ void final_k(const float* __restrict__ hardsum,
                        const float* __restrict__ hardcnt,
                        const float* __restrict__ scal, float* out) {
    float s = 0.f;
    for (int c = threadIdx.x; c < IDN; c += 256)
        s += hardsum[c] / fmaxf(hardcnt[c], 1.0f);
    #pragma unroll
    for (int m = 1; m < 64; m <<= 1) s += __shfl_xor(s, m, 64);
    __shared__ float sb[4];
    int lane = threadIdx.x & 63, w = threadIdx.x >> 6;
    if (lane == 0) sb[w] = s;
    __syncthreads();
    if (threadIdx.x == 0) {
        float an = (sb[0] + sb[1] + sb[2] + sb[3]) / (float)IDN;
        float ap = scal[0] / scal[1];
        out[0] = ap / an;
    }
}

// ---------------- launch ----------------

extern "C" void kernel_launch(void* const* d_in, const int* in_sizes, int n_in,
                              void* d_out, int out_size, void* d_ws, size_t ws_size,
                              hipStream_t stream) {
    const float* inputs  = (const float*)d_in[0];
    const int*   targets = (const int*)d_in[1];
    float* out = (float*)d_out;

    float* ws      = (float*)d_ws;
    float* centers = ws;                              // IDN*DD
    float* c2      = centers + (size_t)IDN * DD;      // IDN
    float* x2      = c2 + IDN;                        // NS
    float* cnt     = x2 + NS;                         // IDN
    float* negsum  = cnt + IDN;                       // IDN
    float* negcnt  = negsum + IDN;                    // IDN
    float* dneg    = negcnt + IDN;                    // IDN
    float* hardsum = dneg + IDN;                      // IDN
    float* hardcnt = hardsum + IDN;                   // IDN
    float* scal    = hardcnt + IDN;                   // 8
    int*   cid     = (int*)(scal + 8);                // IDN
    size_t zero_bytes = (size_t)((char*)(cid + IDN) - (char*)ws);
    hipMemsetAsync(d_ws, 0, zero_bytes, stream);

    count_k<<<NS / 256, 256, 0, stream>>>(targets, cnt);
    accum_k<<<(NS * DD) / 256, 256, 0, stream>>>(inputs, targets, centers);
    fin_centers_k<<<IDN, 256, 0, stream>>>(centers, cnt, targets, c2, cid);
    x2_k<<<NS, 256, 0, stream>>>(inputs, x2);

    dim3 grid(NS / BN, IDN / BM);
    pass_k<1><<<grid, 256, 0, stream>>>(centers, inputs, c2, x2, targets, cid,
                                        negsum, negcnt, dneg, hardsum, hardcnt, scal);
    dneg_k<<<IDN / 256, 256, 0, stream>>>(negsum, negcnt, dneg);
    pass_k<2><<<grid, 256, 0, stream>>>(centers, inputs, c2, x2, targets, cid,
                                        negsum, negcnt, dneg, hardsum, hardcnt, scal);
    final_k<<<1, 256, 0, stream>>>(hardsum, hardcnt, scal, out);
}

// Round 2
// 685.496 us; speedup vs baseline: 2.6618x; 2.6618x over previous
//
#include <hip/hip_runtime.h>
#include <hip/hip_bf16.h>

#define NS   32768
#define DD   256
#define NPOS 4
#define IDN  4096
#define EPSV 1e-6f

typedef __attribute__((ext_vector_type(8))) short short8;
typedef __attribute__((ext_vector_type(4))) float f32x4;

__device__ __forceinline__ unsigned short f2bf(float f) {
    // round-to-nearest-even bf16 (inputs are normal floats, no NaN handling needed)
    unsigned int u = __builtin_bit_cast(unsigned int, f);
    unsigned int r = (u + 0x7FFFu + ((u >> 16) & 1u)) >> 16;
    return (unsigned short)r;
}

__device__ __forceinline__ void gload16(const void* g, void* lds) {
    __builtin_amdgcn_global_load_lds(
        (const __attribute__((address_space(1))) unsigned int*)g,
        (__attribute__((address_space(3))) unsigned int*)lds, 16, 0, 0);
}

// ---------------- prep kernels (MFMA path) ----------------

__global__ void build_idx_k(const int* __restrict__ targets, int* icnt, int* idx) {
    int i = blockIdx.x * 256 + threadIdx.x;
    if (i < NS) {
        int t = targets[i];
        int slot = atomicAdd(&icnt[t], 1);
        if (slot < 16) idx[t * 16 + slot] = i;
    }
}

// convert inputs -> bf16, compute x2 (fp32-exact). 1 wave per row.
__global__ void conv_k(const float* __restrict__ in, unsigned short* __restrict__ Xb,
                       float* __restrict__ x2) {
    int row  = blockIdx.x * 4 + (threadIdx.x >> 6);
    int lane = threadIdx.x & 63;
    const float4 v = *(const float4*)&in[(size_t)row * DD + lane * 4];
    ushort4 u;
    u.x = f2bf(v.x); u.y = f2bf(v.y); u.z = f2bf(v.z); u.w = f2bf(v.w);
    *(ushort4*)&Xb[(size_t)row * DD + lane * 4] = u;
    float sq = v.x * v.x + v.y * v.y + v.z * v.z + v.w * v.w;
    #pragma unroll
    for (int m = 1; m < 64; m <<= 1) sq += __shfl_xor(sq, m, 64);
    if (lane == 0) x2[row] = sq;
}

// per-id mean via gathered index list; writes bf16 centers + fp32 c2 + cid
__global__ void centers_k(const float* __restrict__ in, const int* __restrict__ idx,
                          const int* __restrict__ icnt, const int* __restrict__ targets,
                          unsigned short* __restrict__ Cb, float* __restrict__ c2,
                          int* __restrict__ cid) {
    int c = blockIdx.x, d = threadIdx.x;
    int n = icnt[c]; if (n < 1) n = 1; if (n > 16) n = 16;
    float s = 0.f;
    for (int j = 0; j < n; ++j) s += in[(size_t)idx[c * 16 + j] * DD + d];
    float mean = s / (float)n;
    Cb[(size_t)c * DD + d] = f2bf(mean);
    float sq = mean * mean;
    #pragma unroll
    for (int m = 1; m < 64; m <<= 1) sq += __shfl_xor(sq, m, 64);
    __shared__ float sb[4];
    int lane = d & 63, w = d >> 6;
    if (lane == 0) sb[w] = sq;
    __syncthreads();
    if (d == 0) {
        c2[c] = sb[0] + sb[1] + sb[2] + sb[3];
        cid[c] = targets[c * NPOS];
    }
}

__global__ void dneg_k(const float* __restrict__ negsum,
                       const float* __restrict__ negcnt, float* dneg) {
    int c = blockIdx.x * 256 + threadIdx.x;
    if (c < IDN) dneg[c] = negsum[c] / fmaxf(negcnt[c], 1.0f);
}

// ---------------- MFMA distance + mining pass ----------------
// 128x128 tile, BK=32, 4 waves in 2x2, each wave 64x64 (4x4 frags of 16x16x32)

template <int PASS>
__global__ __launch_bounds__(256)
void mpass_k(const unsigned short* __restrict__ Cb, const unsigned short* __restrict__ Xb,
             const float* __restrict__ c2, const float* __restrict__ x2,
             const int* __restrict__ targets, const int* __restrict__ cid,
             float* negsum, float* negcnt, const float* __restrict__ dneg,
             float* hardsum, float* hardcnt, float* scal) {
    __shared__ unsigned short As[8 * 512];   // 8 frag-blocks x 1024B
    __shared__ unsigned short Bs[8 * 512];
    __shared__ float red[8];

    const int tid = threadIdx.x;
    const int l  = tid & 63;
    const int w  = tid >> 6;      // wave 0..3
    const int wr = w >> 1;        // wave row 0..1
    const int wc = w & 1;         // wave col 0..1
    const int lr = l & 15;
    const int lc = l >> 4;
    const int bm = blockIdx.y, bn = blockIdx.x;

    f32x4 acc[4][4];
    #pragma unroll
    for (int a = 0; a < 4; ++a)
        #pragma unroll
        for (int b = 0; b < 4; ++b) acc[a][b] = (f32x4){0.f, 0.f, 0.f, 0.f};

    // staging: wave w loads frag-blocks {2w, 2w+1} of A and of B.
    // frag-block bo holds rows bo*16..bo*16+15, LDS slot = lane*16B
    //   (lane -> row=l&15, kchunk=l>>4) == exactly the MFMA fragment order.
    const size_t ag0 = (size_t)(bm * 128 + (2 * w) * 16 + lr) * DD + lc * 8;
    const size_t ag1 = ag0 + (size_t)16 * DD;
    const size_t bg0 = (size_t)(bn * 128 + (2 * w) * 16 + lr) * DD + lc * 8;
    const size_t bg1 = bg0 + (size_t)16 * DD;
    unsigned short* aDst0 = &As[(2 * w) * 512];
    unsigned short* aDst1 = &As[(2 * w + 1) * 512];
    unsigned short* bDst0 = &Bs[(2 * w) * 512];
    unsigned short* bDst1 = &Bs[(2 * w + 1) * 512];

    for (int k0 = 0; k0 < DD; k0 += 32) {
        gload16(Cb + ag0 + k0, aDst0);
        gload16(Cb + ag1 + k0, aDst1);
        gload16(Xb + bg0 + k0, bDst0);
        gload16(Xb + bg1 + k0, bDst1);
        __syncthreads();   // compiler drains vmcnt before barrier -> LDS ready
        short8 af[4], bf[4];
        #pragma unroll
        for (int mf = 0; mf < 4; ++mf)
            af[mf] = *(const short8*)&As[(wr * 4 + mf) * 512 + l * 8];
        #pragma unroll
        for (int nf = 0; nf < 4; ++nf)
            bf[nf] = *(const short8*)&Bs[(wc * 4 + nf) * 512 + l * 8];
        #pragma unroll
        for (int mf = 0; mf < 4; ++mf)
            #pragma unroll
            for (int nf = 0; nf < 4; ++nf)
                acc[mf][nf] = __builtin_amdgcn_mfma_f32_16x16x32_bf16(
                    af[mf], bf[nf], acc[mf][nf], 0, 0, 0);
        __syncthreads();   // protect LDS from next-iter staging
    }

    // ---- epilogue: D[row][col], col = lane&15 (+16*nf), row = lc*4+r (+16*mf) ----
    const int gr0 = bm * 128 + wr * 64;
    const int gc0 = bn * 128 + wc * 64;

    float x2v[4]; int tgv[4];
    #pragma unroll
    for (int nf = 0; nf < 4; ++nf) {
        int col = gc0 + nf * 16 + lr;
        x2v[nf] = x2[col];
        tgv[nf] = targets[col];
    }
    float c2v[16]; int cidv[16]; float dnv[16];
    #pragma unroll
    for (int mf = 0; mf < 4; ++mf)
        #pragma unroll
        for (int r = 0; r < 4; ++r) {
            int row = gr0 + mf * 16 + lc * 4 + r;
            c2v[mf * 4 + r]  = c2[row];
            cidv[mf * 4 + r] = cid[row];
            dnv[mf * 4 + r]  = (PASS == 2) ? dneg[row] : 0.f;
        }

    float psum = 0.f, pcnt = 0.f;
    #pragma unroll
    for (int mf = 0; mf < 4; ++mf) {
        float rs[4] = {0.f, 0.f, 0.f, 0.f};
        float rc[4] = {0.f, 0.f, 0.f, 0.f};
        #pragma unroll
        for (int nf = 0; nf < 4; ++nf)
            #pragma unroll
            for (int r = 0; r < 4; ++r) {
                float d2 = fmaf(-2.f, acc[mf][nf][r], c2v[mf * 4 + r] + x2v[nf]);
                float dist = __builtin_amdgcn_sqrtf(fmaxf(d2, 1e-12f));
                bool valid = dist > EPSV;
                bool isneg = (cidv[mf * 4 + r] != tgv[nf]);
                if (PASS == 1) {
                    if (isneg && valid) { rs[r] += dist; rc[r] += 1.f; }
                    else if (!isneg && valid) { psum += dist; pcnt += 1.f; }
                } else {
                    if (isneg && valid && dist < dnv[mf * 4 + r]) { rs[r] += dist; rc[r] += 1.f; }
                }
            }
        #pragma unroll
        for (int r = 0; r < 4; ++r)
            #pragma unroll
            for (int m = 1; m < 16; m <<= 1) {
                rs[r] += __shfl_xor(rs[r], m, 64);
                rc[r] += __shfl_xor(rc[r], m, 64);
            }
        if (lr == 0) {
            #pragma unroll
            for (int r = 0; r < 4; ++r) {
                int row = gr0 + mf * 16 + lc * 4 + r;
                if (PASS == 1) {
                    atomicAdd(&negsum[row], rs[r]);
                    atomicAdd(&negcnt[row], rc[r]);
                } else {
                    atomicAdd(&hardsum[row], rs[r]);
                    atomicAdd(&hardcnt[row], rc[r]);
                }
            }
        }
    }

    if (PASS == 1) {
        #pragma unroll
        for (int m = 1; m < 64; m <<= 1) {
            psum += __shfl_xor(psum, m, 64);
            pcnt += __shfl_xor(pcnt, m, 64);
        }
        if (l == 0) { red[w] = psum; red[4 + w] = pcnt; }
        __syncthreads();
        if (tid == 0) {
            atomicAdd(&scal[0], red[0] + red[1] + red[2] + red[3]);
            atomicAdd(&scal[1], red[4] + red[5] + red[6] + red[7]);
        }
    }
}

__global__ void final_k(const float* __restrict__ hardsum,
                        const float* __restrict__ hardcnt,
                        const float* __restrict__ scal, float* out) {
    float s = 0.f;
    for (int c = threadIdx.x; c < IDN; c += 256)
        s += hardsum[c] / fmaxf(hardcnt[c], 1.0f);
    #pragma unroll
    for (int m = 1; m < 64; m <<= 1) s += __shfl_xor(s, m, 64);
    __shared__ float sb[4];
    int lane = threadIdx.x & 63, w = threadIdx.x >> 6;
    if (lane == 0) sb[w] = s;
    __syncthreads();
    if (threadIdx.x == 0) {
        float an = (sb[0] + sb[1] + sb[2] + sb[3]) / (float)IDN;
        float ap = scal[0] / scal[1];
        out[0] = ap / an;
    }
}

// ---------------- fallback fp32 path (used only if ws too small) ----------------

__global__ void count_k(const int* __restrict__ targets, float* cnt) {
    int i = blockIdx.x * 256 + threadIdx.x;
    if (i < NS) atomicAdd(&cnt[targets[i]], 1.0f);
}

__global__ void accum_k(const float* __restrict__ inputs,
                        const int* __restrict__ targets, float* centers) {
    size_t idx = (size_t)blockIdx.x * 256 + threadIdx.x;
    int i = (int)(idx >> 8);
    int d = (int)(idx & 255);
    atomicAdd(&centers[(size_t)targets[i] * DD + d], inputs[idx]);
}

__global__ void fin_centers_k(float* centers, const float* __restrict__ cnt,
                              const int* __restrict__ targets, float* c2, int* cid) {
    int c = blockIdx.x, d = threadIdx.x;
    float v = centers[(size_t)c * DD + d] / cnt[c];
    centers[(size_t)c * DD + d] = v;
    float sq = v * v;
    #pragma unroll
    for (int m = 1; m < 64; m <<= 1) sq += __shfl_xor(sq, m, 64);
    __shared__ float sb[4];
    int lane = d & 63, w = d >> 6;
    if (lane == 0) sb[w] = sq;
    __syncthreads();
    if (d == 0) { c2[c] = sb[0] + sb[1] + sb[2] + sb[3]; cid[c] = targets[c * NPOS]; }
}

__global__ void x2f_k(const float* __restrict__ inputs, float* x2) {
    int i = blockIdx.x, d = threadIdx.x;
    float v = inputs[(size_t)i * DD + d];
    float sq = v * v;
    #pragma unroll
    for (int m = 1; m < 64; m <<= 1) sq += __shfl_xor(sq, m, 64);
    __shared__ float sb[4];
    int lane = d & 63, w = d >> 6;
    if (lane == 0) sb[w] = sq;
    __syncthreads();
    if (d == 0) x2[i] = sb[0] + sb[1] + sb[2] + sb[3];
}

template <int PASS>
__global__ __launch_bounds__(256)
void pass_k(const float* __restrict__ A, const float* __restrict__ X,
            const float* __restrict__ c2, const float* __restrict__ x2,
            const int* __restrict__ targets, const int* __restrict__ cid,
            float* negsum, float* negcnt, const float* __restrict__ dneg,
            float* hardsum, float* hardcnt, float* scal) {
    __shared__ __align__(16) float Asm[16][128];
    __shared__ __align__(16) float Bsm[16][128];
    __shared__ float red[8];
    const int tid = threadIdx.x;
    const int tx = tid & 15, ty = tid >> 4;
    const int bm = blockIdx.y, bn = blockIdx.x;
    float acc[8][8];
    #pragma unroll
    for (int a = 0; a < 8; ++a)
        #pragma unroll
        for (int b = 0; b < 8; ++b) acc[a][b] = 0.f;
    const int r0 = tid >> 2, k4 = (tid & 3) << 2;
    for (int k0 = 0; k0 < DD; k0 += 16) {
        #pragma unroll
        for (int s = 0; s < 2; ++s) {
            int r = r0 + s * 64;
            float4 av = *(const float4*)&A[(size_t)(bm * 128 + r) * DD + k0 + k4];
            Asm[k4 + 0][r] = av.x; Asm[k4 + 1][r] = av.y;
            Asm[k4 + 2][r] = av.z; Asm[k4 + 3][r] = av.w;
            float4 bv = *(const float4*)&X[(size_t)(bn * 128 + r) * DD + k0 + k4];
            Bsm[k4 + 0][r] = bv.x; Bsm[k4 + 1][r] = bv.y;
            Bsm[k4 + 2][r] = bv.z; Bsm[k4 + 3][r] = bv.w;
        }
        __syncthreads();
        #pragma unroll
        for (int kk = 0; kk < 16; ++kk) {
            float4 a0 = *(const float4*)&Asm[kk][ty * 8];
            float4 a1 = *(const float4*)&Asm[kk][ty * 8 + 4];
            float4 b0 = *(const float4*)&Bsm[kk][tx * 8];
            float4 b1 = *(const float4*)&Bsm[kk][tx * 8 + 4];
            float av[8] = {a0.x, a0.y, a0.z, a0.w, a1.x, a1.y, a1.z, a1.w};
            float bv[8] = {b0.x, b0.y, b0.z, b0.w, b1.x, b1.y, b1.z, b1.w};
            #pragma unroll
            for (int a = 0; a < 8; ++a)
                #pragma unroll
                for (int b = 0; b < 8; ++b) acc[a][b] = fmaf(av[a], bv[b], acc[a][b]);
        }
        __syncthreads();
    }
    const int gr = bm * 128 + ty * 8, gc = bn * 128 + tx * 8;
    float x2v[8]; int tg[8];
    #pragma unroll
    for (int b = 0; b < 8; ++b) { x2v[b] = x2[gc + b]; tg[b] = targets[gc + b]; }
    float psum = 0.f, pcnt = 0.f;
    #pragma unroll
    for (int a = 0; a < 8; ++a) {
        const int c = gr + a;
        const int cd = cid[c];
        const float c2v = c2[c];
        float dn = (PASS == 2) ? dneg[c] : 0.f;
        float s0 = 0.f, s1 = 0.f;
        #pragma unroll
        for (int b = 0; b < 8; ++b) {
            float d2 = c2v + x2v[b] - 2.f * acc[a][b];
            float dist = sqrtf(fmaxf(d2, 1e-12f));
            bool valid = dist > EPSV;
            bool neg = (cd != tg[b]);
            if (PASS == 1) {
                if (neg) { if (valid) { s0 += dist; s1 += 1.f; } }
                else if (valid) { psum += dist; pcnt += 1.f; }
            } else {
                if (neg && valid && dist < dn) { s0 += dist; s1 += 1.f; }
            }
        }
        #pragma unroll
        for (int m = 1; m < 16; m <<= 1) { s0 += __shfl_xor(s0, m, 64); s1 += __shfl_xor(s1, m, 64); }
        if (tx == 0) {
            if (PASS == 1) { atomicAdd(&negsum[c], s0); atomicAdd(&negcnt[c], s1); }
            else { atomicAdd(&hardsum[c], s0); atomicAdd(&hardcnt[c], s1); }
        }
    }
    if (PASS == 1) {
        #pragma unroll
        for (int m = 1; m < 64; m <<= 1) { psum += __shfl_xor(psum, m, 64); pcnt += __shfl_xor(pcnt, m, 64); }
        int lane = tid & 63, w = tid >> 6;
        if (lane == 0) { red[w] = psum; red[4 + w] = pcnt; }
        __syncthreads();
        if (tid == 0) {
            atomicAdd(&scal[0], red[0] + red[1] + red[2] + red[3]);
            atomicAdd(&scal[1], red[4] + red[5] + red[6] + red[7]);
        }
    }
}

// ---------------- launch ----------------

extern "C" void kernel_launch(void* const* d_in, const int* in_sizes, int n_in,
                              void* d_out, int out_size, void* d_ws, size_t ws_size,
                              hipStream_t stream) {
    const float* inputs  = (const float*)d_in[0];
    const int*   targets = (const int*)d_in[1];
    float* out = (float*)d_out;

    char* p = (char*)d_ws;
    unsigned short* Xb = (unsigned short*)p;  p += (size_t)NS * DD * 2;
    unsigned short* Cb = (unsigned short*)p;  p += (size_t)IDN * DD * 2;
    float* x2   = (float*)p;  p += (size_t)NS * 4;
    float* c2   = (float*)p;  p += (size_t)IDN * 4;
    float* dneg = (float*)p;  p += (size_t)IDN * 4;
    int*   cid  = (int*)p;    p += (size_t)IDN * 4;
    int*   idx  = (int*)p;    p += (size_t)IDN * 16 * 4;
    char* zp = p;
    int*   icnt    = (int*)p;    p += (size_t)IDN * 4;
    float* negsum  = (float*)p;  p += (size_t)IDN * 4;
    float* negcnt  = (float*)p;  p += (size_t)IDN * 4;
    float* hardsum = (float*)p;  p += (size_t)IDN * 4;
    float* hardcnt = (float*)p;  p += (size_t)IDN * 4;
    float* scal    = (float*)p;  p += 64;
    size_t required = (size_t)(p - (char*)d_ws);

    if (ws_size >= required) {
        hipMemsetAsync(zp, 0, (size_t)(p - zp), stream);
        build_idx_k<<<NS / 256, 256, 0, stream>>>(targets, icnt, idx);
        conv_k<<<NS / 4, 256, 0, stream>>>(inputs, Xb, x2);
        centers_k<<<IDN, 256, 0, stream>>>(inputs, idx, icnt, targets, Cb, c2, cid);
        dim3 grid(NS / 128, IDN / 128);
        mpass_k<1><<<grid, 256, 0, stream>>>(Cb, Xb, c2, x2, targets, cid,
                                             negsum, negcnt, dneg, hardsum, hardcnt, scal);
        dneg_k<<<IDN / 256, 256, 0, stream>>>(negsum, negcnt, dneg);
        mpass_k<2><<<grid, 256, 0, stream>>>(Cb, Xb, c2, x2, targets, cid,
                                             negsum, negcnt, dneg, hardsum, hardcnt, scal);
        final_k<<<1, 256, 0, stream>>>(hardsum, hardcnt, scal, out);
    } else {
        // fp32 fallback (round-1 layout)
        float* ws      = (float*)d_ws;
        float* centers = ws;
        float* c2f     = centers + (size_t)IDN * DD;
        float* x2f     = c2f + IDN;
        float* cntf    = x2f + NS;
        float* negsumf = cntf + IDN;
        float* negcntf = negsumf + IDN;
        float* dnegf   = negcntf + IDN;
        float* hardsumf= dnegf + IDN;
        float* hardcntf= hardsumf + IDN;
        float* scalf   = hardcntf + IDN;
        int*   cidf    = (int*)(scalf + 8);
        size_t zero_bytes = (size_t)((char*)(cidf + IDN) - (char*)ws);
        hipMemsetAsync(d_ws, 0, zero_bytes, stream);
        count_k<<<NS / 256, 256, 0, stream>>>(targets, cntf);
        accum_k<<<(NS * DD) / 256, 256, 0, stream>>>(inputs, targets, centers);
        fin_centers_k<<<IDN, 256, 0, stream>>>(centers, cntf, targets, c2f, cidf);
        x2f_k<<<NS, 256, 0, stream>>>(inputs, x2f);
        dim3 grid(NS / 128, IDN / 128);
        pass_k<1><<<grid, 256, 0, stream>>>(centers, inputs, c2f, x2f, targets, cidf,
                                            negsumf, negcntf, dnegf, hardsumf, hardcntf, scalf);
        dneg_k<<<IDN / 256, 256, 0, stream>>>(negsumf, negcntf, dnegf);
        pass_k<2><<<grid, 256, 0, stream>>>(centers, inputs, c2f, x2f, targets, cidf,
                                            negsumf, negcntf, dnegf, hardsumf, hardcntf, scalf);
        final_k<<<1, 256, 0, stream>>>(hardsumf, hardcntf, scalf, out);
    }
}

// Round 3
// 467.084 us; speedup vs baseline: 3.9065x; 1.4676x over previous
//
#include <hip/hip_runtime.h>
#include <hip/hip_bf16.h>

#define NS   32768
#define DD   256
#define NPOS 4
#define IDN  4096

typedef __attribute__((ext_vector_type(8))) short short8;
typedef __attribute__((ext_vector_type(4))) float f32x4;

__device__ __forceinline__ unsigned short f2bf(float f) {
    unsigned int u = __builtin_bit_cast(unsigned int, f);
    unsigned int r = (u + 0x7FFFu + ((u >> 16) & 1u)) >> 16;
    return (unsigned short)r;
}

__device__ __forceinline__ void gload16(const void* g, void* lds) {
    __builtin_amdgcn_global_load_lds(
        (const __attribute__((address_space(1))) unsigned int*)g,
        (__attribute__((address_space(3))) unsigned int*)lds, 16, 0, 0);
}

// ---------------- prep kernels ----------------

__global__ void build_idx_k(const int* __restrict__ targets, int* icnt, int* idx) {
    int i = blockIdx.x * 256 + threadIdx.x;
    if (i < NS) {
        int t = targets[i];
        int slot = atomicAdd(&icnt[t], 1);
        if (slot < 16) idx[t * 16 + slot] = i;
    }
}

__global__ void conv_k(const float* __restrict__ in, unsigned short* __restrict__ Xb,
                       float* __restrict__ x2) {
    int row  = blockIdx.x * 4 + (threadIdx.x >> 6);
    int lane = threadIdx.x & 63;
    const float4 v = *(const float4*)&in[(size_t)row * DD + lane * 4];
    ushort4 u;
    u.x = f2bf(v.x); u.y = f2bf(v.y); u.z = f2bf(v.z); u.w = f2bf(v.w);
    *(ushort4*)&Xb[(size_t)row * DD + lane * 4] = u;
    float sq = v.x * v.x + v.y * v.y + v.z * v.z + v.w * v.w;
    #pragma unroll
    for (int m = 1; m < 64; m <<= 1) sq += __shfl_xor(sq, m, 64);
    if (lane == 0) x2[row] = sq;
}

__global__ void centers_k(const float* __restrict__ in, const int* __restrict__ idx,
                          const int* __restrict__ icnt, const int* __restrict__ targets,
                          unsigned short* __restrict__ Cb, float* __restrict__ c2,
                          int* __restrict__ cid) {
    int c = blockIdx.x, d = threadIdx.x;
    int n = icnt[c]; if (n < 1) n = 1; if (n > 16) n = 16;
    float s = 0.f;
    for (int j = 0; j < n; ++j) s += in[(size_t)idx[c * 16 + j] * DD + d];
    float mean = s / (float)n;
    Cb[(size_t)c * DD + d] = f2bf(mean);
    float sq = mean * mean;
    #pragma unroll
    for (int m = 1; m < 64; m <<= 1) sq += __shfl_xor(sq, m, 64);
    __shared__ float sb[4];
    int lane = d & 63, w = d >> 6;
    if (lane == 0) sb[w] = sq;
    __syncthreads();
    if (d == 0) {
        c2[c] = sb[0] + sb[1] + sb[2] + sb[3];
        cid[c] = targets[c * NPOS];
    }
}

__global__ void dneg_k(const float* __restrict__ negsum,
                       const float* __restrict__ negcnt, float* dneg) {
    int c = blockIdx.x * 256 + threadIdx.x;
    if (c < IDN) dneg[c] = negsum[c] / fmaxf(negcnt[c], 1.0f);
}

// ---------------- A-resident N-streaming MFMA pass ----------------
// 256 blocks (32 row-blocks x 8 col-chunks), 512 threads (8 waves, 2x4).
// A panel 128x256 bf16 in LDS (staged once, ONE barrier total).
// B fragments loaded straight from global (L2-resident). No hot-loop barriers.
// Mining sums accumulate in registers across the whole 4096-col sweep.

template <int PASS>
__global__ __launch_bounds__(512, 2)
void mpass_k(const unsigned short* __restrict__ Cb, const unsigned short* __restrict__ Xb,
             const float* __restrict__ c2, const float* __restrict__ x2,
             const int* __restrict__ targets, const int* __restrict__ cid,
             float* negsum, float* negcnt, const float* __restrict__ dneg,
             float* hardsum, float* hardcnt, float* scal) {
    __shared__ unsigned short As[8 * 8 * 64 * 8];   // [kstep][fragblock][lane*8] = 64KB
    __shared__ float red[16];

    const int tid = threadIdx.x;
    const int l  = tid & 63;
    const int w  = tid >> 6;      // wave 0..7
    const int wr = w >> 2;        // 0..1 : row half (64 rows)
    const int wc = w & 3;         // 0..3 : col quarter (64 cols per step)
    const int lr = l & 15;
    const int lc = l >> 4;
    const int bid = blockIdx.x;
    const int bn = bid & 7;       // col chunk == XCD (round-robin dispatch)
    const int bm = bid >> 3;      // row block 0..31

    // ---- stage A panel, fragment-block layout; wave w owns fragblock w ----
    {
        const unsigned short* src = Cb + (size_t)(bm * 128 + w * 16 + lr) * DD + lc * 8;
        #pragma unroll
        for (int s = 0; s < 8; ++s)     // s = kstep
            gload16(src + s * 32, &As[(s * 8 + w) * 512]);
    }
    __syncthreads();   // the only barrier

    // ---- per-row constants (rows fixed for whole kernel) ----
    const int gr0 = bm * 128 + wr * 64;
    float c2v[16]; int cidv[16]; float dnv[16];
    #pragma unroll
    for (int mf = 0; mf < 4; ++mf)
        #pragma unroll
        for (int r = 0; r < 4; ++r) {
            int row = gr0 + mf * 16 + lc * 4 + r;
            c2v[mf * 4 + r]  = c2[row];
            cidv[mf * 4 + r] = cid[row];
            dnv[mf * 4 + r]  = (PASS == 2) ? dneg[row] : 0.f;
        }

    float rs[16], rc[16];
    #pragma unroll
    for (int i = 0; i < 16; ++i) { rs[i] = 0.f; rc[i] = 0.f; }
    float psum = 0.f, pcnt = 0.f;

    const int colw0 = bn * 4096 + wc * 64;   // this wave's first col, step 0

    for (int step = 0; step < 16; ++step) {
        const int col0 = colw0 + step * 256;

        float x2v[4]; int tgv[4];
        #pragma unroll
        for (int nf = 0; nf < 4; ++nf) {
            int cc = col0 + nf * 16 + lr;
            x2v[nf] = x2[cc];
            tgv[nf] = targets[cc];
        }

        f32x4 acc[4][4];
        #pragma unroll
        for (int a = 0; a < 4; ++a)
            #pragma unroll
            for (int b = 0; b < 4; ++b) acc[a][b] = (f32x4){0.f, 0.f, 0.f, 0.f};

        const unsigned short* bbase = Xb + (size_t)(col0 + lr) * DD + lc * 8;

        #pragma unroll
        for (int kk = 0; kk < 8; ++kk) {
            short8 af[4], bf[4];
            #pragma unroll
            for (int mf = 0; mf < 4; ++mf)
                af[mf] = *(const short8*)&As[((kk * 8 + wr * 4 + mf) * 64 + l) * 8];
            #pragma unroll
            for (int nf = 0; nf < 4; ++nf)
                bf[nf] = *(const short8*)(bbase + (size_t)(nf * 16) * DD + kk * 32);
            #pragma unroll
            for (int mf = 0; mf < 4; ++mf)
                #pragma unroll
                for (int nf = 0; nf < 4; ++nf)
                    acc[mf][nf] = __builtin_amdgcn_mfma_f32_16x16x32_bf16(
                        af[mf], bf[nf], acc[mf][nf], 0, 0, 0);
        }

        // ---- fused epilogue: accumulate into persistent registers ----
        #pragma unroll
        for (int mf = 0; mf < 4; ++mf)
            #pragma unroll
            for (int nf = 0; nf < 4; ++nf)
                #pragma unroll
                for (int r = 0; r < 4; ++r) {
                    const int i = mf * 4 + r;
                    float d2 = fmaf(-2.f, acc[mf][nf][r], c2v[i] + x2v[nf]);
                    float dist = __builtin_amdgcn_sqrtf(fmaxf(d2, 1e-12f));
                    bool valid = d2 > 1e-12f;          // == (dist > 1e-6)
                    bool isneg = (cidv[i] != tgv[nf]);
                    if (PASS == 1) {
                        float mn = (valid && isneg) ? 1.f : 0.f;
                        float mp = (valid && !isneg) ? 1.f : 0.f;
                        rs[i] = fmaf(mn, dist, rs[i]);  rc[i] += mn;
                        psum  = fmaf(mp, dist, psum);   pcnt  += mp;
                    } else {
                        float mh = (valid && isneg && dist < dnv[i]) ? 1.f : 0.f;
                        rs[i] = fmaf(mh, dist, rs[i]);  rc[i] += mh;
                    }
                }
    }

    // ---- block-end reduction: over the 16 lr-lanes sharing the same rows ----
    #pragma unroll
    for (int i = 0; i < 16; ++i)
        #pragma unroll
        for (int m = 1; m < 16; m <<= 1) {
            rs[i] += __shfl_xor(rs[i], m, 64);
            rc[i] += __shfl_xor(rc[i], m, 64);
        }
    if (lr == 0) {
        float* S = (PASS == 1) ? negsum : hardsum;
        float* C = (PASS == 1) ? negcnt : hardcnt;
        #pragma unroll
        for (int mf = 0; mf < 4; ++mf)
            #pragma unroll
            for (int r = 0; r < 4; ++r) {
                int row = gr0 + mf * 16 + lc * 4 + r;
                atomicAdd(&S[row], rs[mf * 4 + r]);
                atomicAdd(&C[row], rc[mf * 4 + r]);
            }
    }

    if (PASS == 1) {
        #pragma unroll
        for (int m = 1; m < 64; m <<= 1) {
            psum += __shfl_xor(psum, m, 64);
            pcnt += __shfl_xor(pcnt, m, 64);
        }
        if (l == 0) { red[w] = psum; red[8 + w] = pcnt; }
        __syncthreads();
        if (tid == 0) {
            float s0 = 0.f, s1 = 0.f;
            #pragma unroll
            for (int i = 0; i < 8; ++i) { s0 += red[i]; s1 += red[8 + i]; }
            atomicAdd(&scal[0], s0);
            atomicAdd(&scal[1], s1);
        }
    }
}

__global__ void final_k(const float* __restrict__ hardsum,
                        const float* __restrict__ hardcnt,
                        const float* __restrict__ scal, float* out) {
    float s = 0.f;
    for (int c = threadIdx.x; c < IDN; c += 256)
        s += hardsum[c] / fmaxf(hardcnt[c], 1.0f);
    #pragma unroll
    for (int m = 1; m < 64; m <<= 1) s += __shfl_xor(s, m, 64);
    __shared__ float sb[4];
    int lane = threadIdx.x & 63, w = threadIdx.x >> 6;
    if (lane == 0) sb[w] = s;
    __syncthreads();
    if (threadIdx.x == 0) {
        float an = (sb[0] + sb[1] + sb[2] + sb[3]) / (float)IDN;
        float ap = scal[0] / scal[1];
        out[0] = ap / an;
    }
}

// ---------------- launch ----------------

extern "C" void kernel_launch(void* const* d_in, const int* in_sizes, int n_in,
                              void* d_out, int out_size, void* d_ws, size_t ws_size,
                              hipStream_t stream) {
    const float* inputs  = (const float*)d_in[0];
    const int*   targets = (const int*)d_in[1];
    float* out = (float*)d_out;

    char* p = (char*)d_ws;
    unsigned short* Xb = (unsigned short*)p;  p += (size_t)NS * DD * 2;
    unsigned short* Cb = (unsigned short*)p;  p += (size_t)IDN * DD * 2;
    float* x2   = (float*)p;  p += (size_t)NS * 4;
    float* c2   = (float*)p;  p += (size_t)IDN * 4;
    float* dneg = (float*)p;  p += (size_t)IDN * 4;
    int*   cid  = (int*)p;    p += (size_t)IDN * 4;
    int*   idx  = (int*)p;    p += (size_t)IDN * 16 * 4;
    char* zp = p;
    int*   icnt    = (int*)p;    p += (size_t)IDN * 4;
    float* negsum  = (float*)p;  p += (size_t)IDN * 4;
    float* negcnt  = (float*)p;  p += (size_t)IDN * 4;
    float* hardsum = (float*)p;  p += (size_t)IDN * 4;
    float* hardcnt = (float*)p;  p += (size_t)IDN * 4;
    float* scal    = (float*)p;  p += 64;

    hipMemsetAsync(zp, 0, (size_t)(p - zp), stream);
    build_idx_k<<<NS / 256, 256, 0, stream>>>(targets, icnt, idx);
    conv_k<<<NS / 4, 256, 0, stream>>>(inputs, Xb, x2);
    centers_k<<<IDN, 256, 0, stream>>>(inputs, idx, icnt, targets, Cb, c2, cid);

    mpass_k<1><<<256, 512, 0, stream>>>(Cb, Xb, c2, x2, targets, cid,
                                        negsum, negcnt, dneg, hardsum, hardcnt, scal);
    dneg_k<<<IDN / 256, 256, 0, stream>>>(negsum, negcnt, dneg);
    mpass_k<2><<<256, 512, 0, stream>>>(Cb, Xb, c2, x2, targets, cid,
                                        negsum, negcnt, dneg, hardsum, hardcnt, scal);
    final_k<<<1, 256, 0, stream>>>(hardsum, hardcnt, scal, out);
}